// Round 1
// baseline (29352.133 us; speedup 1.0000x reference)
//
#include <hip/hip_runtime.h>
#include <math.h>

#define NT 4096      // n_train
#define MT 8192      // n_test
#define NB 128       // cholesky block
#define NBLK 32      // NT/NB
#define TBM 128      // f32 gemm tile M (chol only)
#define TBN 64       // f32 gemm tile N
#define TBK 32       // f32 gemm tile K
#define SRPB 64      // solve: rows per update block

typedef unsigned short u16;
typedef short v8s __attribute__((ext_vector_type(8)));
typedef float v4f __attribute__((ext_vector_type(4)));

// ---------------- helpers ----------------
__device__ __forceinline__ float bf2f(u16 h) {
  return __uint_as_float(((unsigned)h) << 16);
}
__device__ __forceinline__ u16 f2bf(float x) {  // RNE f32->bf16
  unsigned u = __float_as_uint(x);
  u += 0x7fffu + ((u >> 16) & 1u);
  return (u16)(u >> 16);
}
__device__ __forceinline__ void split1(float x, u16& h, u16& l) {
  h = f2bf(x);
  l = f2bf(x - bf2f(h));
}
__device__ __forceinline__ float softplusf(float x) { return log1pf(expf(x)); }

__device__ __forceinline__ void load8bf(const u16* __restrict__ p, float* f) {
  ushort4 u0 = *(const ushort4*)p;
  ushort4 u1 = *(const ushort4*)(p + 4);
  f[0] = bf2f(u0.x); f[1] = bf2f(u0.y); f[2] = bf2f(u0.z); f[3] = bf2f(u0.w);
  f[4] = bf2f(u1.x); f[5] = bf2f(u1.y); f[6] = bf2f(u1.z); f[7] = bf2f(u1.w);
}

// dtype-polymorphic input readers (flag: 1 = f32 inputs, 0 = bf16 inputs)
__device__ __forceinline__ float getsc(const void* p, int f32) {
  return f32 ? *(const float*)p : bf2f(*(const u16*)p);
}
__device__ __forceinline__ float getel(const void* p, int i, int f32) {
  return f32 ? ((const float*)p)[i] : bf2f(((const u16*)p)[i]);
}
__device__ __forceinline__ void load_pt(const void* xb, int idx, int f32, float* f) {
  if (f32) {
    const float4* q = (const float4*)xb;
    float4 a = q[idx * 2], b = q[idx * 2 + 1];
    f[0] = a.x; f[1] = a.y; f[2] = a.z; f[3] = a.w;
    f[4] = b.x; f[5] = b.y; f[6] = b.z; f[7] = b.w;
  } else {
    load8bf((const u16*)xb + idx * 8, f);
  }
}

__global__ void detect_dtype(const u16* __restrict__ xt, int* __restrict__ flag) {
  if (threadIdx.x == 0) {
    int f = 0;
    for (int i = 0; i < 32; i++) if (xt[i] >= 0x4000) f = 1;
    flag[0] = f;
  }
}

// ---------------- kernel-matrix builders ----------------
__global__ void build_K(const void* __restrict__ xt, const void* __restrict__ w,
                        const void* __restrict__ rls, const void* __restrict__ rvar,
                        const void* __restrict__ rnv, float* __restrict__ K,
                        const int* __restrict__ flag) {
  int f32 = flag[0];
  int j = blockIdx.x * 16 + threadIdx.x;
  int i = blockIdx.y * 16 + threadIdx.y;
  float ls  = softplusf(getsc(rls, f32));
  float var = softplusf(getsc(rvar, f32));
  float cc  = -0.5f / (ls * ls);
  float v;
  if (i == j) {
    v = var + softplusf(getsc(rnv, f32)) + 1e-6f;
  } else {
    float a[8], b[8];
    load_pt(xt, i, f32, a);
    load_pt(xt, j, f32, b);
    float d = 0.f;
#pragma unroll
    for (int q = 0; q < 8; q++) { float t = a[q] - b[q]; d += t * t; }
    v = var * expf(cc * d) * getel(w, i, f32) * getel(w, j, f32);
  }
  K[(size_t)i * NT + j] = v;
}

// Kst[j][i] = w_i * k(x_i, x_j), built DIRECTLY as split bf16 hi/lo planes [MT][NT]
__global__ void build_Kst(const void* __restrict__ xt, const void* __restrict__ xs,
                          const void* __restrict__ w, const void* __restrict__ rls,
                          const void* __restrict__ rvar,
                          u16* __restrict__ hi, u16* __restrict__ lo,
                          const int* __restrict__ flag) {
  int f32 = flag[0];
  int i = blockIdx.x * 16 + threadIdx.x;   // train (fast dim -> coalesced)
  int j = blockIdx.y * 16 + threadIdx.y;   // test
  float ls  = softplusf(getsc(rls, f32));
  float var = softplusf(getsc(rvar, f32));
  float cc  = -0.5f / (ls * ls);
  float a[8], b[8];
  load_pt(xt, i, f32, a);
  load_pt(xs, j, f32, b);
  float d = 0.f;
#pragma unroll
  for (int q = 0; q < 8; q++) { float t = a[q] - b[q]; d += t * t; }
  float v = getel(w, i, f32) * var * expf(cc * d);
  size_t o = (size_t)j * NT + i;
  u16 h, l; split1(v, h, l);
  hi[o] = h; lo[o] = l;
}

// ---------------- fused diag-block Cholesky + inverse (unchanged) ----------------
__global__ void __launch_bounds__(256) potrf_invert(float* __restrict__ Kg,
                                                    float* __restrict__ Wall, int kb) {
  __shared__ float At[NB * NB];
  __shared__ float Wv[NB * NB];
  int tid = threadIdx.x;
  int r0 = kb * NB;
  for (int idx = tid; idx < NB * NB; idx += 256) {
    int k = idx >> 7, i = idx & 127;
    At[idx] = Kg[(size_t)(r0 + k) * NT + r0 + i];
    Wv[idx] = (k == i) ? 1.f : 0.f;
  }
  __syncthreads();
  for (int j = 0; j < NB; j++) {
    float inv = 1.0f / At[j * NB + j];
    int nel = (NB - 1 - j) << 7;
    for (int idx = tid; idx < nel; idx += 256) {
      int k = j + 1 + (idx >> 7);
      int i = idx & 127;
      if (i >= k) At[k * NB + i] -= At[j * NB + i] * (At[j * NB + k] * inv);
    }
    __syncthreads();
  }
  for (int t = 0; t < NB; t++) {
    float invd = 1.0f / At[t * NB + t];
    int nel = (NB - 1 - t) << 7;
    for (int idx = tid; idx < nel; idx += 256) {
      int i = t + 1 + (idx >> 7);
      int c = idx & 127;
      Wv[i * NB + c] -= (At[t * NB + i] * invd) * Wv[t * NB + c];
    }
    __syncthreads();
  }
  for (int idx = tid; idx < NB * NB; idx += 256) {
    int k = idx >> 7, i = idx & 127;
    if (i >= k) {
      float s = sqrtf(At[k * NB + k]);
      Kg[(size_t)(r0 + i) * NT + r0 + k] = (i == k) ? s : At[idx] / s;
    }
  }
  float* Wg = Wall + (size_t)kb * NB * NB;
  for (int idx = tid; idx < NB * NB; idx += 256) {
    int i = idx >> 7;
    Wg[idx] = Wv[idx] / sqrtf(At[i * NB + i]);
  }
}

__global__ void copy_panel(const float* __restrict__ Kg, float* __restrict__ S,
                           int t0, int rows, int kb) {
  int idx = blockIdx.x * 256 + threadIdx.x;
  if (idx < rows * NB) {
    int r = idx >> 7, c = idx & 127;
    S[idx] = Kg[(size_t)(t0 + r) * NT + kb * NB + c];
  }
}

// ---------------- f32 GEMM (chol only): C (op)= A[MxK] @ B[NxK]^T ----------------
template<int SUB, int SYRK>
__global__ void __launch_bounds__(256) gemm_nt(const float* __restrict__ A, int lda,
                                               const float* __restrict__ B, int ldb,
                                               float* __restrict__ C, int ldc, int Kdim) {
  int c0 = blockIdx.x * TBN;
  int r0 = blockIdx.y * TBM;
  if (SYRK && c0 > r0 + TBM - 1) return;
  __shared__ float As[TBK][TBM + 4];
  __shared__ float Bs[TBK][TBN + 4];
  int tid = threadIdx.x;
  int tx = tid & 15, ty = tid >> 4;
  float acc[8][4];
#pragma unroll
  for (int r = 0; r < 8; r++)
#pragma unroll
    for (int c = 0; c < 4; c++) acc[r][c] = 0.f;

  int am = tid & 127, ah = tid >> 7;
  int bc = tid & 63,  bh = tid >> 6;

  for (int kt = 0; kt < Kdim; kt += TBK) {
#pragma unroll
    for (int q = 0; q < 4; q++) {
      int s = ah * 4 + q;
      float4 v = *(const float4*)&A[(size_t)(r0 + am) * lda + kt + s * 4];
      As[s * 4 + 0][am] = v.x; As[s * 4 + 1][am] = v.y;
      As[s * 4 + 2][am] = v.z; As[s * 4 + 3][am] = v.w;
    }
#pragma unroll
    for (int q = 0; q < 2; q++) {
      int s = bh * 2 + q;
      float4 v = *(const float4*)&B[(size_t)(c0 + bc) * ldb + kt + s * 4];
      Bs[s * 4 + 0][bc] = v.x; Bs[s * 4 + 1][bc] = v.y;
      Bs[s * 4 + 2][bc] = v.z; Bs[s * 4 + 3][bc] = v.w;
    }
    __syncthreads();
#pragma unroll
    for (int k = 0; k < TBK; k++) {
      float a[8], b[4];
      *(float4*)&a[0] = *(const float4*)&As[k][ty * 8];
      *(float4*)&a[4] = *(const float4*)&As[k][ty * 8 + 4];
      *(float4*)&b[0] = *(const float4*)&Bs[k][tx * 4];
#pragma unroll
      for (int r = 0; r < 8; r++)
#pragma unroll
        for (int c = 0; c < 4; c++) acc[r][c] += a[r] * b[c];
    }
    __syncthreads();
  }
#pragma unroll
  for (int r = 0; r < 8; r++) {
    float* cp = &C[(size_t)(r0 + ty * 8 + r) * ldc + c0 + tx * 4];
    if (SUB) {
      float4 o = *(const float4*)cp;
      o.x -= acc[r][0]; o.y -= acc[r][1]; o.z -= acc[r][2]; o.w -= acc[r][3];
      *(float4*)cp = o;
    } else {
      float4 o; o.x = acc[r][0]; o.y = acc[r][1]; o.z = acc[r][2]; o.w = acc[r][3];
      *(float4*)cp = o;
    }
  }
}

// ---------------- multi-WG blocked triangular solves for alpha (unchanged) ----------------
__global__ void init_r(const void* __restrict__ y, float* __restrict__ r,
                       const int* __restrict__ flag) {
  int i = blockIdx.x * 256 + threadIdx.x;
  r[i] = getel(y, i, flag[0]);
}

__global__ void __launch_bounds__(256) fwd_step(const float* __restrict__ Lg,
                                                const float* __restrict__ Wall,
                                                float* __restrict__ r,
                                                float* __restrict__ z, int kb) {
  __shared__ float ts[NB];
  __shared__ float part[256];
  int tid = threadIdx.x;
  int r0 = kb * NB;
  {
    int row = tid >> 1, half = tid & 1;
    const float* Wr = Wall + (size_t)kb * NB * NB + row * NB + half * 64;
    const float* rv = r + r0 + half * 64;
    float acc = 0.f;
#pragma unroll
    for (int c = 0; c < 64; c += 4) {
      float4 wv = *(const float4*)&Wr[c];
      float4 xv = *(const float4*)&rv[c];
      acc += wv.x * xv.x + wv.y * xv.y + wv.z * xv.z + wv.w * xv.w;
    }
    part[tid] = acc;
    __syncthreads();
    if (half == 0) ts[row] = part[tid] + part[tid + 1];
    __syncthreads();
  }
  if (blockIdx.x == 0) {
    if (tid < NB) z[r0 + tid] = ts[tid];
    return;
  }
  int base = r0 + NB + (blockIdx.x - 1) * SRPB;
  int wv_ = tid >> 6, lane = tid & 63;
  for (int rr = wv_; rr < SRPB; rr += 4) {
    int row = base + rr;
    const float* Lr = Lg + (size_t)row * NT + r0;
    float acc = Lr[lane] * ts[lane] + Lr[lane + 64] * ts[lane + 64];
#pragma unroll
    for (int off = 32; off > 0; off >>= 1) acc += __shfl_down(acc, off, 64);
    if (lane == 0) r[row] -= acc;
  }
}

__global__ void __launch_bounds__(256) bwd_step(const float* __restrict__ Lg,
                                                const float* __restrict__ Wall,
                                                float* __restrict__ z,
                                                float* __restrict__ a, int kb) {
  __shared__ float ts[NB];
  __shared__ float part[256];
  int tid = threadIdx.x;
  int r0 = kb * NB;
  {
    int col = tid & 127, half = tid >> 7;
    const float* Wb = Wall + (size_t)kb * NB * NB;
    float acc = 0.f;
#pragma unroll 4
    for (int rr = half * 64; rr < half * 64 + 64; rr++)
      acc += Wb[rr * NB + col] * z[r0 + rr];
    part[tid] = acc;
    __syncthreads();
    if (half == 0) ts[col] = part[tid] + part[tid + 128];
    __syncthreads();
  }
  if (blockIdx.x == 0) {
    if (tid < NB) a[r0 + tid] = ts[tid];
    return;
  }
  int cb = blockIdx.x - 1;
  int col = cb * NB + (tid & 127);
  int half = tid >> 7;
  float acc = 0.f;
#pragma unroll 4
  for (int jr = half * 64; jr < half * 64 + 64; jr++)
    acc += Lg[(size_t)(r0 + jr) * NT + col] * ts[jr];
  part[tid] = acc;
  __syncthreads();
  if (half == 0) z[col] -= part[tid] + part[tid + 128];
}

// ---------------- Wall -> split planes ----------------
__global__ void conv_W(const float* __restrict__ src, u16* __restrict__ hi,
                       u16* __restrict__ lo) {
  int idx = (blockIdx.x * 256 + threadIdx.x) * 4;
  float4 v = *(const float4*)&src[idx];
  ushort4 h, l;
  split1(v.x, h.x, l.x); split1(v.y, h.y, l.y);
  split1(v.z, h.z, l.z); split1(v.w, h.w, l.w);
  *(ushort4*)&hi[idx] = h;
  *(ushort4*)&lo[idx] = l;
}

// ---------------- mu[j] = dot(Kst[j][:], alpha) ----------------
__global__ void __launch_bounds__(256) mu_dot(const u16* __restrict__ hi,
                                              const u16* __restrict__ lo,
                                              const float* __restrict__ alpha,
                                              float* __restrict__ mu) {
  int lane = threadIdx.x & 63, wv = threadIdx.x >> 6;
  int j = blockIdx.x * 4 + wv;
  const u16* ph = hi + (size_t)j * NT;
  const u16* pl = lo + (size_t)j * NT;
  float s = 0.f;
  for (int c = lane * 4; c < NT; c += 256) {
    ushort4 h = *(const ushort4*)&ph[c];
    ushort4 l = *(const ushort4*)&pl[c];
    float4 a = *(const float4*)&alpha[c];
    s += (bf2f(h.x) + bf2f(l.x)) * a.x + (bf2f(h.y) + bf2f(l.y)) * a.y
       + (bf2f(h.z) + bf2f(l.z)) * a.z + (bf2f(h.w) + bf2f(l.w)) * a.w;
  }
#pragma unroll
  for (int off = 32; off > 0; off >>= 1) s += __shfl_down(s, off, 64);
  if (lane == 0) mu[j] = s;
}

// ---------------- split-bf16 MFMA GEMM: C (op)= A[MxK] @ B[NxK]^T ----------------
// A from hi/lo planes [.][lda]; B from planes (BF32=0) or f32 (BF32=1, on-the-fly split).
// MODE 0: store result into C hi/lo planes (trsm z-block, in-place-safe: BN=128 full)
// MODE 1: C planes -= result (trsm trailing update, RMW in split form)
// MODE 2: Cf = Kss(xs) - result, lower blocks + mirror (cov epilogue)
// Tile 128x128xBK64, 4 waves of 64x64, mfma_f32_16x16x32_bf16 (m97-family pattern).
template<int MODE, int BF32>
__global__ void __launch_bounds__(256) mm_bf16(
    const u16* __restrict__ Ah, const u16* __restrict__ Al, int lda,
    const u16* __restrict__ Bh, const u16* __restrict__ Bl,
    const float* __restrict__ Bf, int ldb,
    u16* __restrict__ Chi, u16* __restrict__ Clo, float* __restrict__ Cf,
    int ldc, int Kdim,
    const void* __restrict__ xs, const void* __restrict__ rls,
    const void* __restrict__ rvar, const int* __restrict__ flag) {
  int c0 = blockIdx.x * 128;
  int r0 = blockIdx.y * 128;
  if (MODE == 2 && r0 < c0) return;   // upper blocks: covered by mirror
  __shared__ u16 L[4][128 * 64];      // Ahi, Alo, Bhi, Blo tiles (64 KB)
  int tid = threadIdx.x;
  int lane = tid & 63, wv = tid >> 6;
  int wr = wv >> 1, wc = wv & 1;      // wave -> 64x64 sub-tile
  int lr = lane & 15, lk = lane >> 4;

  v4f acc[4][4];
  v4f zero = {0.f, 0.f, 0.f, 0.f};
#pragma unroll
  for (int mi = 0; mi < 4; mi++)
#pragma unroll
    for (int ni = 0; ni < 4; ni++) acc[mi][ni] = zero;

  for (int kt = 0; kt < Kdim; kt += 64) {
    int4 rga[8], rgb[8];
#pragma unroll
    for (int p = 0; p < 4; p++) {   // A planes: 1024 8-elem chunks
      int ch = p * 256 + tid;
      int row = ch >> 3, sl = ch & 7;
      size_t o = (size_t)(r0 + row) * lda + kt + sl * 8;
      rga[p]     = *(const int4*)(Ah + o);
      rga[p + 4] = *(const int4*)(Al + o);
    }
    if (BF32 == 0) {
#pragma unroll
      for (int p = 0; p < 4; p++) {
        int ch = p * 256 + tid;
        int row = ch >> 3, sl = ch & 7;
        size_t o = (size_t)(c0 + row) * ldb + kt + sl * 8;
        rgb[p]     = *(const int4*)(Bh + o);
        rgb[p + 4] = *(const int4*)(Bl + o);
      }
    } else {
#pragma unroll
      for (int p = 0; p < 8; p++) {  // f32 B: 2048 float4 chunks
        int ch = p * 256 + tid;
        int row = ch >> 4, f4 = ch & 15;
        rgb[p] = *(const int4*)(Bf + (size_t)(c0 + row) * ldb + kt + f4 * 4);
      }
    }
    __syncthreads();                 // prior compute done with LDS
#pragma unroll
    for (int p = 0; p < 4; p++) {
      int ch = p * 256 + tid;
      int row = ch >> 3, sl = ch & 7;
      int off = row * 64 + ((sl ^ (row & 7)) * 8);   // XOR bank swizzle
      *(int4*)&L[0][off] = rga[p];
      *(int4*)&L[1][off] = rga[p + 4];
      if (BF32 == 0) {
        *(int4*)&L[2][off] = rgb[p];
        *(int4*)&L[3][off] = rgb[p + 4];
      }
    }
    if (BF32 == 1) {
#pragma unroll
      for (int p = 0; p < 8; p++) {
        int ch = p * 256 + tid;
        int row = ch >> 4, f4 = ch & 15;
        const float* v = (const float*)&rgb[p];
        ushort4 h, l;
        split1(v[0], h.x, l.x); split1(v[1], h.y, l.y);
        split1(v[2], h.z, l.z); split1(v[3], h.w, l.w);
        int sl = f4 >> 1, half = f4 & 1;
        int off = row * 64 + ((sl ^ (row & 7)) * 8) + half * 4;
        *(ushort4*)&L[2][off] = h;
        *(ushort4*)&L[3][off] = l;
      }
    }
    __syncthreads();
#pragma unroll
    for (int ks = 0; ks < 2; ks++) {
      v8s afh[4], afl[4], bfh[4], bfl[4];
#pragma unroll
      for (int mi = 0; mi < 4; mi++) {
        int row = wr * 64 + mi * 16 + lr;
        int sl = (ks * 4 + lk) ^ (row & 7);
        afh[mi] = *(const v8s*)&L[0][row * 64 + sl * 8];
        afl[mi] = *(const v8s*)&L[1][row * 64 + sl * 8];
      }
#pragma unroll
      for (int ni = 0; ni < 4; ni++) {
        int row = wc * 64 + ni * 16 + lr;
        int sl = (ks * 4 + lk) ^ (row & 7);
        bfh[ni] = *(const v8s*)&L[2][row * 64 + sl * 8];
        bfl[ni] = *(const v8s*)&L[3][row * 64 + sl * 8];
      }
#pragma unroll
      for (int mi = 0; mi < 4; mi++)
#pragma unroll
        for (int ni = 0; ni < 4; ni++) {
          acc[mi][ni] = __builtin_amdgcn_mfma_f32_16x16x32_bf16(afh[mi], bfh[ni], acc[mi][ni], 0, 0, 0);
          acc[mi][ni] = __builtin_amdgcn_mfma_f32_16x16x32_bf16(afh[mi], bfl[ni], acc[mi][ni], 0, 0, 0);
          acc[mi][ni] = __builtin_amdgcn_mfma_f32_16x16x32_bf16(afl[mi], bfh[ni], acc[mi][ni], 0, 0, 0);
        }
    }
  }

  // epilogue: D lane map (verified): row = lk*4 + r, col = lr
  if (MODE == 2) {
    int f32 = flag[0];
    float ls  = softplusf(getsc(rls, f32));
    float var = softplusf(getsc(rvar, f32));
    float cc  = -0.5f / (ls * ls);
#pragma unroll
    for (int mi = 0; mi < 4; mi++) {
#pragma unroll
      for (int r = 0; r < 4; r++) {
        int grow = r0 + wr * 64 + mi * 16 + lk * 4 + r;
        float xr[8];
        load_pt(xs, grow, f32, xr);
#pragma unroll
        for (int ni = 0; ni < 4; ni++) {
          int gcol = c0 + wc * 64 + ni * 16 + lr;
          float xc[8];
          load_pt(xs, gcol, f32, xc);
          float d = 0.f;
#pragma unroll
          for (int q = 0; q < 8; q++) { float t = xr[q] - xc[q]; d += t * t; }
          float kss = var * expf(cc * d);
          if (grow == gcol) kss += 1e-6f;
          float ov = kss - acc[mi][ni][r];
          Cf[(size_t)grow * ldc + gcol] = ov;
          if (grow > gcol) Cf[(size_t)gcol * ldc + grow] = ov;
        }
      }
    }
  } else {
#pragma unroll
    for (int mi = 0; mi < 4; mi++) {
#pragma unroll
      for (int r = 0; r < 4; r++) {
        int grow = r0 + wr * 64 + mi * 16 + lk * 4 + r;
#pragma unroll
        for (int ni = 0; ni < 4; ni++) {
          int gcol = c0 + wc * 64 + ni * 16 + lr;
          size_t o = (size_t)grow * ldc + gcol;
          float nv;
          if (MODE == 0) {
            nv = acc[mi][ni][r];
          } else {
            nv = (bf2f(Chi[o]) + bf2f(Clo[o])) - acc[mi][ni][r];
          }
          u16 h, l; split1(nv, h, l);
          Chi[o] = h; Clo[o] = l;
        }
      }
    }
  }
}

// ---------------- host ----------------
extern "C" void kernel_launch(void* const* d_in, const int* in_sizes, int n_in,
                              void* d_out, int out_size, void* d_ws, size_t ws_size,
                              hipStream_t stream) {
  (void)in_sizes; (void)n_in; (void)out_size; (void)ws_size;
  const void* xt  = d_in[0];
  const void* y   = d_in[1];
  const void* w   = d_in[2];
  const void* xs  = d_in[3];
  const void* rls = d_in[4];
  const void* rva = d_in[5];
  const void* rnv = d_in[6];

  float* mu_out  = (float*)d_out;        // [MT] f32
  float* cov_out = mu_out + MT;          // [MT*MT] f32

  // workspace (~198 MB total):
  float* Kf   = (float*)d_ws;                              // NT*NT f32 (64 MB)
  float* Wall = Kf + (size_t)NT * NT;                      // NBLK*NB*NB f32
  float* S    = Wall + (size_t)NBLK * NB * NB;             // (NT-NB)*NB f32
  float* rbuf = S + (size_t)(NT - NB) * NB;                // NT
  float* zbuf = rbuf + NT;                                 // NT
  float* abuf = zbuf + NT;                                 // NT
  int*   flag = (int*)(abuf + NT);                         // 4 ints (keep 16B align)
  u16* Whi  = (u16*)(flag + 4);                            // NBLK*NB*NB bf16
  u16* Wlo  = Whi + (size_t)NBLK * NB * NB;
  u16* Vthi = Wlo + (size_t)NBLK * NB * NB;                // [MT][NT] bf16 (64 MB)
  u16* Vtlo = Vthi + (size_t)MT * NT;                      // [MT][NT] bf16 (64 MB)

  detect_dtype<<<1, 64, 0, stream>>>((const u16*)xt, flag);
  build_K<<<dim3(NT / 16, NT / 16), dim3(16, 16), 0, stream>>>(xt, w, rls, rva, rnv, Kf, flag);
  build_Kst<<<dim3(NT / 16, MT / 16), dim3(16, 16), 0, stream>>>(xt, xs, w, rls, rva,
                                                                 Vthi, Vtlo, flag);

  // blocked Cholesky of Kf (lower), with explicit diag-block inverses (f32, unchanged)
  for (int kb = 0; kb < NBLK; kb++) {
    potrf_invert<<<1, 256, 0, stream>>>(Kf, Wall, kb);
    int t0 = (kb + 1) * NB;
    int rows = NT - t0;
    if (rows > 0) {
      copy_panel<<<(rows * NB) / 256, 256, 0, stream>>>(Kf, S, t0, rows, kb);
      gemm_nt<0, 0><<<dim3(NB / TBN, rows / TBM), 256, 0, stream>>>(
          S, NB, Wall + (size_t)kb * NB * NB, NB,
          Kf + (size_t)t0 * NT + kb * NB, NT, NB);
      gemm_nt<1, 1><<<dim3(rows / TBN, rows / TBM), 256, 0, stream>>>(
          Kf + (size_t)t0 * NT + kb * NB, NT,
          Kf + (size_t)t0 * NT + kb * NB, NT,
          Kf + (size_t)t0 * NT + t0, NT, NB);
    }
  }

  conv_W<<<(NBLK * NB * NB) / 1024, 256, 0, stream>>>(Wall, Whi, Wlo);

  // alpha = (L L^T)^{-1} y
  init_r<<<NT / 256, 256, 0, stream>>>(y, rbuf, flag);
  for (int kb = 0; kb < NBLK; kb++) {
    int nupd = (NT - (kb + 1) * NB) / SRPB;
    fwd_step<<<1 + nupd, 256, 0, stream>>>(Kf, Wall, rbuf, zbuf, kb);
  }
  for (int kb = NBLK - 1; kb >= 0; kb--) {
    bwd_step<<<1 + kb, 256, 0, stream>>>(Kf, Wall, zbuf, abuf, kb);
  }

  // mu from ORIGINAL Kst planes (before trsm overwrites them)
  mu_dot<<<MT / 4, 256, 0, stream>>>(Vthi, Vtlo, abuf, mu_out);

  // v^T = Kst solved against L (right-looking blocked forward substitution),
  // kept in split-bf16 planes throughout. MFMA split GEMMs.
  for (int kb = 0; kb < NBLK; kb++) {
    // z-block: Vt[:,kb] = Vt[:,kb] @ W_kb^T   (reads+writes same cols; BN=128 => safe)
    mm_bf16<0, 0><<<dim3(1, MT / 128), 256, 0, stream>>>(
        Vthi + kb * NB, Vtlo + kb * NB, NT,
        Whi + (size_t)kb * NB * NB, Wlo + (size_t)kb * NB * NB, nullptr, NB,
        Vthi + kb * NB, Vtlo + kb * NB, nullptr, NT, NB,
        nullptr, nullptr, nullptr, nullptr);
    int t0 = (kb + 1) * NB;
    int rows = NT - t0;
    if (rows > 0) {
      // trailing: Vt[:,t0+n] -= Vt[:,kb] @ L21^T  (B from f32 Kf, on-the-fly split)
      mm_bf16<1, 1><<<dim3(rows / 128, MT / 128), 256, 0, stream>>>(
          Vthi + kb * NB, Vtlo + kb * NB, NT,
          nullptr, nullptr, Kf + (size_t)t0 * NT + kb * NB, NT,
          Vthi + t0, Vtlo + t0, nullptr, NT, NB,
          nullptr, nullptr, nullptr, nullptr);
    }
  }

  // cov = Kss - v^T v  (split-bf16 MFMA SYRK, fused Kss, lower + mirror)
  mm_bf16<2, 0><<<dim3(MT / 128, MT / 128), 256, 0, stream>>>(
      Vthi, Vtlo, NT, Vthi, Vtlo, nullptr, NT,
      nullptr, nullptr, cov_out, MT, NT,
      xs, rls, rva, flag);
}